// Round 7
// baseline (405.613 us; speedup 1.0000x reference)
//
#include <hip/hip_runtime.h>
#include <hip/hip_bf16.h>
#include <math.h>

constexpr int B = 32, T = 256, D = 2048, H = 16, DK = 64;
constexpr size_t BHTD = (size_t)B * H * T * DK;  // 8388608
constexpr int NC8 = (B * T * D) / 8;             // 2097152
constexpr int NW8 = (H * DK * D) / 8;            // 262144
constexpr int NB8 = (H * D) / 8;                 // 4096

typedef __attribute__((ext_vector_type(8))) short short8;
typedef __attribute__((ext_vector_type(4))) float f32x4;

// ---------------------------------------------------------------------------
// one grid-stride cast kernel: content -> c_bf; [k_w;v_w;b_w;ts_w] -> w_bf
// ---------------------------------------------------------------------------
__global__ __launch_bounds__(256) void cast_all(
    const float* __restrict__ content, const float* __restrict__ k_w,
    const float* __restrict__ v_w, const float* __restrict__ b_w,
    const float* __restrict__ ts_w, __hip_bfloat16* __restrict__ c_bf,
    __hip_bfloat16* __restrict__ w_bf) {
  const int total = NC8 + 2 * NW8 + 2 * NB8;
  int i = blockIdx.x * blockDim.x + threadIdx.x;
  const int stride = gridDim.x * blockDim.x;
  for (; i < total; i += stride) {
    const float* src;
    __hip_bfloat16* dst;
    int idx;
    if (i < NC8) { src = content; dst = c_bf; idx = i; }
    else if (i < NC8 + NW8) { src = k_w; dst = w_bf; idx = i - NC8; }
    else if (i < NC8 + 2 * NW8) {
      src = v_w; dst = w_bf + (size_t)1024 * D; idx = i - NC8 - NW8;
    } else if (i < NC8 + 2 * NW8 + NB8) {
      src = b_w; dst = w_bf + (size_t)2048 * D; idx = i - NC8 - 2 * NW8;
    } else {
      src = ts_w; dst = w_bf + (size_t)2064 * D; idx = i - NC8 - 2 * NW8 - NB8;
    }
    const float4 x = ((const float4*)src)[2 * idx];
    const float4 y = ((const float4*)src)[2 * idx + 1];
    __hip_bfloat16 tmp[8];
    tmp[0] = __float2bfloat16(x.x); tmp[1] = __float2bfloat16(x.y);
    tmp[2] = __float2bfloat16(x.z); tmp[3] = __float2bfloat16(x.w);
    tmp[4] = __float2bfloat16(y.x); tmp[5] = __float2bfloat16(y.y);
    tmp[6] = __float2bfloat16(y.z); tmp[7] = __float2bfloat16(y.w);
    *(uint4*)(dst + 8 * (size_t)idx) = *(const uint4*)tmp;
  }
}

// ---------------------------------------------------------------------------
// bf16 MFMA GEMM, hybrid staging: A via double-buffered LDS DMA (one barrier
// per K-iter), B fragments direct global->VGPR with 1-iter prefetch (L1/L2
// pipe, parallel to LDS pipe). XCD-band grid swizzle as R6.
// ---------------------------------------------------------------------------
__global__ __launch_bounds__(256) void gemm_bf16(
    const __hip_bfloat16* __restrict__ A, const __hip_bfloat16* __restrict__ Wc,
    float* __restrict__ outk, const float* __restrict__ b_b,
    const float* __restrict__ ts_b, const float* __restrict__ hd,
    float* __restrict__ beta_out, float* __restrict__ gamma_out) {
  __shared__ __hip_bfloat16 As[2][128 * 32];
  const int tid = threadIdx.x;
  const int bid = blockIdx.x;
  const int g = bid & 7, local = bid >> 3;
  const int nt = local >> 3, mt = g * 8 + (local & 7);
  const int m0 = mt * 128, n0 = nt * 128;
  const int w = tid >> 6, lane = tid & 63;
  const int wm = w & 1, wn = w >> 1;
  const int fr = lane & 15, fq = lane >> 4;
  const int srow = w * 16 + (lane >> 2);
  const int skc = (lane & 3) * 8;

  // B fragment row pointers (k-offset fq*8 baked in)
  const __hip_bfloat16* brow[4];
#pragma unroll
  for (int j = 0; j < 4; ++j)
    brow[j] = Wc + (size_t)(n0 + wn * 64 + j * 16 + fr) * D + fq * 8;

  // prologue: prefetch B(k0=0), DMA A tile 0 into buf 0
  short8 bnx[4];
#pragma unroll
  for (int j = 0; j < 4; ++j) bnx[j] = *(const short8*)(brow[j]);
#pragma unroll
  for (int p = 0; p < 2; ++p) {
    __builtin_amdgcn_global_load_lds(
        (const __attribute__((address_space(1))) void*)(A + (size_t)(m0 + p * 64 + srow) * D + skc),
        (__attribute__((address_space(3))) void*)((char*)As[0] + p * 4096 + w * 1024), 16, 0, 0);
  }
  __syncthreads();  // tile 0 in LDS (barrier drains vmcnt)

  f32x4 acc[4][4] = {};
  for (int k0 = 0; k0 < D; k0 += 32) {
    const int buf = (k0 >> 5) & 1;
    short8 bcur[4];
#pragma unroll
    for (int j = 0; j < 4; ++j) bcur[j] = bnx[j];
    if (k0 + 32 < D) {
      // prefetch next A tile into other buffer + next B frags into regs
#pragma unroll
      for (int p = 0; p < 2; ++p) {
        __builtin_amdgcn_global_load_lds(
            (const __attribute__((address_space(1))) void*)(A + (size_t)(m0 + p * 64 + srow) * D + k0 + 32 + skc),
            (__attribute__((address_space(3))) void*)((char*)As[buf ^ 1] + p * 4096 + w * 1024), 16, 0, 0);
      }
#pragma unroll
      for (int j = 0; j < 4; ++j) bnx[j] = *(const short8*)(brow[j] + k0 + 32);
    }
    short8 af[4];
#pragma unroll
    for (int i = 0; i < 4; ++i)
      af[i] = *(const short8*)(As[buf] + (wm * 64 + i * 16 + fr) * 32 + fq * 8);
#pragma unroll
    for (int i = 0; i < 4; ++i)
#pragma unroll
      for (int j = 0; j < 4; ++j)
        acc[i][j] = __builtin_amdgcn_mfma_f32_16x16x32_bf16(af[i], bcur[j], acc[i][j], 0, 0, 0);
    __syncthreads();  // drains next-tile DMA; guards buf reuse
  }
  if (n0 < 2048) {  // k/v projection tiles
#pragma unroll
    for (int i = 0; i < 4; ++i) {
      const int mbase = m0 + wm * 64 + i * 16 + fq * 4;
#pragma unroll
      for (int j = 0; j < 4; ++j) {
        const int n = n0 + wn * 64 + j * 16 + fr;
        const int h = (n >> 6) & 15, dk = n & 63;
        float* dst = outk + (size_t)(n >> 10) * BHTD;
#pragma unroll
        for (int r = 0; r < 4; ++r) {
          const int mm = mbase + r;
          const int b = mm >> 8, t = mm & 255;
          dst[(((size_t)b * H + h) * T + t) * DK + dk] = acc[i][j][r];
        }
      }
    }
  } else if (wn == 0) {  // beta/gamma tile: cols 0..15 beta, 16..31 gamma
    const int h = fr;
    const float bias_b = b_b[h];
    const float bias_g = ts_b[h] + hd[h];
#pragma unroll
    for (int i = 0; i < 4; ++i) {
      const int mbase = m0 + wm * 64 + i * 16 + fq * 4;
#pragma unroll
      for (int r = 0; r < 4; ++r) {
        const int mm = mbase + r;
        const int b = mm >> 8, t = mm & 255;
        const size_t oo = ((size_t)b * H + h) * T + t;
        beta_out[oo] = 1.f / (1.f + __expf(-(acc[i][0][r] + bias_b)));
        gamma_out[oo] = 1.f / (1.f + __expf(-(acc[i][1][r] + bias_g)));
      }
    }
  }
}

// ---------------------------------------------------------------------------
// Chunked solve (unchanged): per-chunk K staging, 2 blocks/CU.
// ---------------------------------------------------------------------------
__device__ __forceinline__ int cgi(int r, int g) {  // float4 index, chunk-local
  return r * 16 + (g & 8) + ((g ^ (r >> 2)) & 7);
}
__device__ __forceinline__ float rdlane(float x, int j) {
  return __int_as_float(__builtin_amdgcn_readlane(__float_as_int(x), j));
}

__global__ __launch_bounds__(256, 2) void solve_write(
    const float* __restrict__ kg, const float* __restrict__ vg,
    const float* __restrict__ betag, const float* __restrict__ gammag,
    const float* __restrict__ Wold, float* __restrict__ Wnew) {
  __shared__ float kC[64 * 64];
  __shared__ float Mm[64][68];
  __shared__ float Ss[64][68];
  __shared__ float Uu[64][68];
  __shared__ float s_beta[256], s_cl[256];
  float4* kC4 = (float4*)kC;

  const int tid = threadIdx.x;
  const int bh = blockIdx.x;
  const size_t base = (size_t)bh * T * DK;
  const int lane = tid & 63, wv = tid >> 6;
  const int th = tid >> 4, tl = tid & 15;

  s_beta[tid] = betag[(size_t)bh * T + tid];
  s_cl[tid] = __logf(fmaxf(gammag[(size_t)bh * T + tid], 1e-8f));
  __syncthreads();
  if (tid == 0) {
    float run = 0.f;
    for (int t = 0; t < T; ++t) { run += s_cl[t]; s_cl[t] = run; }
  }
  {  // M init = Wold^T
    const float* Wo = Wold + (size_t)bh * DK * DK;
    const int d = tid & 63, v0 = (tid >> 6) * 16;
#pragma unroll
    for (int u = 0; u < 16; ++u) Mm[d][v0 + u] = Wo[(size_t)(v0 + u) * DK + d];
  }
  __syncthreads();

  for (int c = 0; c < 4; ++c) {
    const int c0 = c * 64;
    const float oc = (c == 0) ? 0.f : s_cl[c0 - 1];
    const float on = s_cl[c0 + 63];

    {  // stage chunk K, normalized; 4 lanes per row
      const int r = tid >> 2, p = tid & 3;
      const float4* kp = (const float4*)(kg + base + (size_t)(c0 + r) * DK + p * 16);
      float4 x0 = kp[0], x1 = kp[1], x2 = kp[2], x3 = kp[3];
      float nrm = x0.x * x0.x + x0.y * x0.y + x0.z * x0.z + x0.w * x0.w +
                  x1.x * x1.x + x1.y * x1.y + x1.z * x1.z + x1.w * x1.w +
                  x2.x * x2.x + x2.y * x2.y + x2.z * x2.z + x2.w * x2.w +
                  x3.x * x3.x + x3.y * x3.y + x3.z * x3.z + x3.w * x3.w;
      nrm += __shfl_xor(nrm, 1, 64);
      nrm += __shfl_xor(nrm, 2, 64);
      const float rn = 1.f / fmaxf(sqrtf(nrm), 1e-12f);
      kC4[cgi(r, 4 * p + 0)] = make_float4(x0.x * rn, x0.y * rn, x0.z * rn, x0.w * rn);
      kC4[cgi(r, 4 * p + 1)] = make_float4(x1.x * rn, x1.y * rn, x1.z * rn, x1.w * rn);
      kC4[cgi(r, 4 * p + 2)] = make_float4(x2.x * rn, x2.y * rn, x2.z * rn, x2.w * rn);
      kC4[cgi(r, 4 * p + 3)] = make_float4(x3.x * rn, x3.y * rn, x3.z * rn, x3.w * rn);
    }
    __syncthreads();

    {  // P1: S = K_c K_c^T
      float accS[4][4] = {};
      for (int g = 0; g < 16; ++g) {
        float av[4][4], bv[4][4];
#pragma unroll
        for (int r = 0; r < 4; ++r) *(float4*)av[r] = kC4[cgi(4 * th + r, g)];
#pragma unroll
        for (int r = 0; r < 4; ++r) *(float4*)bv[r] = kC4[cgi(4 * tl + r, g)];
#pragma unroll
        for (int i = 0; i < 4; ++i)
#pragma unroll
          for (int j = 0; j < 4; ++j)
#pragma unroll
            for (int d = 0; d < 4; ++d) accS[i][j] += av[i][d] * bv[j][d];
      }
#pragma unroll
      for (int r = 0; r < 4; ++r)
        *(float4*)&Ss[4 * th + r][4 * tl] =
            make_float4(accS[r][0], accS[r][1], accS[r][2], accS[r][3]);
    }
    {  // P2: U = V_chunk - e^{ci} K_c M
      float acc2[4][4] = {};
      for (int dg = 0; dg < 16; ++dg) {
        float kv[4][4], mv[4][4];
#pragma unroll
        for (int r = 0; r < 4; ++r) *(float4*)kv[r] = kC4[cgi(4 * th + r, dg)];
#pragma unroll
        for (int r = 0; r < 4; ++r) *(float4*)mv[r] = *(const float4*)&Mm[4 * dg + r][4 * tl];
#pragma unroll
        for (int i = 0; i < 4; ++i)
#pragma unroll
          for (int d = 0; d < 4; ++d)
#pragma unroll
            for (int u = 0; u < 4; ++u) acc2[i][u] += kv[i][d] * mv[d][u];
      }
#pragma unroll
      for (int r = 0; r < 4; ++r) {
        const int gi = c0 + 4 * th + r;
        const float ci = (gi == 0) ? 0.f : s_cl[gi - 1] - oc;
        const float eci = __expf(ci);
        float4 vv = *(const float4*)(vg + base + (size_t)gi * DK + 4 * tl);
        *(float4*)&Uu[4 * th + r][4 * tl] =
            make_float4(vv.x - eci * acc2[r][0], vv.y - eci * acc2[r][1],
                        vv.z - eci * acc2[r][2], vv.w - eci * acc2[r][3]);
      }
    }
    __syncthreads();
    {  // P3: intra-chunk solve; wave wv owns v-range [16wv,16wv+16)
      const int gi = c0 + lane;
      const int v0 = wv * 16;
      float rhs[16];
#pragma unroll
      for (int u = 0; u < 4; ++u)
        *(float4*)&rhs[4 * u] = *(const float4*)&Uu[lane][v0 + 4 * u];
      const float ci = (gi == 0) ? 0.f : s_cl[gi - 1] - oc;
      const float ecl = __expf(ci);
      const float wgt = s_beta[gi] * __expf(-(s_cl[gi] - oc));
      for (int j = 0; j < 63; ++j) {
        const float wj = rdlane(wgt, j);
        const float sv = Ss[j][lane];
        const float co = (lane > j) ? ecl * wj * sv : 0.f;
#pragma unroll
        for (int u = 0; u < 16; ++u) rhs[u] -= co * rdlane(rhs[u], j);
      }
      const float ul = wgt * __expf(on - oc);
#pragma unroll
      for (int u = 0; u < 4; ++u)
        *(float4*)&Uu[lane][v0 + 4 * u] =
            make_float4(ul * rhs[4 * u], ul * rhs[4 * u + 1],
                        ul * rhs[4 * u + 2], ul * rhs[4 * u + 3]);
    }
    __syncthreads();
    {  // P4: M = e^{on-oc} M + K_c^T U
      const float rc = __expf(on - oc);
      const int d0 = 4 * th;
      float macc[4][4];
#pragma unroll
      for (int r = 0; r < 4; ++r) {
        float4 m4 = *(const float4*)&Mm[d0 + r][4 * tl];
        macc[r][0] = rc * m4.x; macc[r][1] = rc * m4.y;
        macc[r][2] = rc * m4.z; macc[r][3] = rc * m4.w;
      }
      for (int j = 0; j < 64; ++j) {
        float kj[4], uj[4];
        *(float4*)kj = kC4[cgi(j, th)];
        *(float4*)uj = *(const float4*)&Uu[j][4 * tl];
#pragma unroll
        for (int d = 0; d < 4; ++d)
#pragma unroll
          for (int u = 0; u < 4; ++u) macc[d][u] += kj[d] * uj[u];
      }
#pragma unroll
      for (int r = 0; r < 4; ++r)
        *(float4*)&Mm[d0 + r][4 * tl] =
            make_float4(macc[r][0], macc[r][1], macc[r][2], macc[r][3]);
    }
    __syncthreads();
  }
  {  // epilogue: W_new[v][d] = M[d][v]
    const int v = tid >> 2, d0 = (tid & 3) * 16;
    float* op = Wnew + (size_t)bh * DK * DK + (size_t)v * DK + d0;
#pragma unroll
    for (int u = 0; u < 4; ++u)
      *(float4*)(op + 4 * u) =
          make_float4(Mm[d0 + 4 * u + 0][v], Mm[d0 + 4 * u + 1][v],
                      Mm[d0 + 4 * u + 2][v], Mm[d0 + 4 * u + 3][v]);
  }
}

// ---------------------------------------------------------------------------
extern "C" void kernel_launch(void* const* d_in, const int* in_sizes, int n_in,
                              void* d_out, int out_size, void* d_ws, size_t ws_size,
                              hipStream_t stream) {
  const float* W_old = (const float*)d_in[0];
  const float* content = (const float*)d_in[1];
  const float* k_w = (const float*)d_in[2];
  const float* v_w = (const float*)d_in[3];
  const float* b_w = (const float*)d_in[4];
  const float* b_b = (const float*)d_in[5];
  const float* ts_w = (const float*)d_in[6];
  const float* ts_b = (const float*)d_in[7];
  const float* hd = (const float*)d_in[8];
  float* out = (float*)d_out;

  float* ws_k = (float*)d_ws;
  float* ws_v = ws_k + BHTD;
  float* ws_beta = ws_v + BHTD;
  float* ws_gamma = ws_beta + (size_t)B * H * T;
  __hip_bfloat16* c_bf = (__hip_bfloat16*)(ws_gamma + (size_t)B * H * T);
  __hip_bfloat16* w_bf = c_bf + (size_t)B * T * D;  // 2176 x 2048 region

  cast_all<<<2048, 256, 0, stream>>>(content, k_w, v_w, b_w, ts_w, c_bf, w_bf);
  gemm_bf16<<<dim3(1088), 256, 0, stream>>>(c_bf, w_bf, ws_k, b_b, ts_b, hd,
                                            ws_beta, ws_gamma);
  solve_write<<<dim3(B * H), 256, 0, stream>>>(ws_k, ws_v, ws_beta, ws_gamma,
                                               W_old, out);
}

// Round 8
// 339.190 us; speedup vs baseline: 1.1958x; 1.1958x over previous
//
#include <hip/hip_runtime.h>
#include <hip/hip_bf16.h>
#include <math.h>

constexpr int B = 32, T = 256, D = 2048, H = 16, DK = 64;
constexpr size_t BHTD = (size_t)B * H * T * DK;  // 8388608
constexpr int NC8 = (B * T * D) / 8;             // 2097152
constexpr int NW8 = (H * DK * D) / 8;            // 262144
constexpr int NB8 = (H * D) / 8;                 // 4096

typedef __attribute__((ext_vector_type(8))) short short8;
typedef __attribute__((ext_vector_type(4))) float f32x4;

// ---------------------------------------------------------------------------
// one grid-stride cast kernel: content -> c_bf; [k_w;v_w;b_w;ts_w] -> w_bf
// ---------------------------------------------------------------------------
__global__ __launch_bounds__(256) void cast_all(
    const float* __restrict__ content, const float* __restrict__ k_w,
    const float* __restrict__ v_w, const float* __restrict__ b_w,
    const float* __restrict__ ts_w, __hip_bfloat16* __restrict__ c_bf,
    __hip_bfloat16* __restrict__ w_bf) {
  const int total = NC8 + 2 * NW8 + 2 * NB8;
  int i = blockIdx.x * blockDim.x + threadIdx.x;
  const int stride = gridDim.x * blockDim.x;
  for (; i < total; i += stride) {
    const float* src;
    __hip_bfloat16* dst;
    int idx;
    if (i < NC8) { src = content; dst = c_bf; idx = i; }
    else if (i < NC8 + NW8) { src = k_w; dst = w_bf; idx = i - NC8; }
    else if (i < NC8 + 2 * NW8) {
      src = v_w; dst = w_bf + (size_t)1024 * D; idx = i - NC8 - NW8;
    } else if (i < NC8 + 2 * NW8 + NB8) {
      src = b_w; dst = w_bf + (size_t)2048 * D; idx = i - NC8 - 2 * NW8;
    } else {
      src = ts_w; dst = w_bf + (size_t)2064 * D; idx = i - NC8 - 2 * NW8 - NB8;
    }
    const float4 x = ((const float4*)src)[2 * idx];
    const float4 y = ((const float4*)src)[2 * idx + 1];
    __hip_bfloat16 tmp[8];
    tmp[0] = __float2bfloat16(x.x); tmp[1] = __float2bfloat16(x.y);
    tmp[2] = __float2bfloat16(x.z); tmp[3] = __float2bfloat16(x.w);
    tmp[4] = __float2bfloat16(y.x); tmp[5] = __float2bfloat16(y.y);
    tmp[6] = __float2bfloat16(y.z); tmp[7] = __float2bfloat16(y.w);
    *(uint4*)(dst + 8 * (size_t)idx) = *(const uint4*)tmp;
  }
}

// ---------------------------------------------------------------------------
// bf16 MFMA GEMM — exact R6 version (best measured: 159 us).
// ---------------------------------------------------------------------------
__global__ __launch_bounds__(256) void gemm_bf16(
    const __hip_bfloat16* __restrict__ A, const __hip_bfloat16* __restrict__ Wc,
    float* __restrict__ outk, const float* __restrict__ b_b,
    const float* __restrict__ ts_b, const float* __restrict__ hd,
    float* __restrict__ beta_out, float* __restrict__ gamma_out) {
  __shared__ __hip_bfloat16 As[128 * 32];
  __shared__ __hip_bfloat16 Bs[128 * 32];
  const int tid = threadIdx.x;
  const int bid = blockIdx.x;
  const int g = bid & 7, local = bid >> 3;
  const int nt = local >> 3, mt = g * 8 + (local & 7);
  const int m0 = mt * 128, n0 = nt * 128;
  const int w = tid >> 6, lane = tid & 63;
  const int wm = w & 1, wn = w >> 1;
  const int fr = lane & 15, fq = lane >> 4;
  const int srow = w * 16 + (lane >> 2);
  const int skc = (lane & 3) * 8;
  f32x4 acc[4][4] = {};
  for (int k0 = 0; k0 < D; k0 += 32) {
#pragma unroll
    for (int p = 0; p < 2; ++p) {
      const int row = p * 64 + srow;
      const int lo = p * 4096 + w * 1024;
      __builtin_amdgcn_global_load_lds(
          (const __attribute__((address_space(1))) void*)(A + (size_t)(m0 + row) * D + k0 + skc),
          (__attribute__((address_space(3))) void*)((char*)As + lo), 16, 0, 0);
      __builtin_amdgcn_global_load_lds(
          (const __attribute__((address_space(1))) void*)(Wc + (size_t)(n0 + row) * D + k0 + skc),
          (__attribute__((address_space(3))) void*)((char*)Bs + lo), 16, 0, 0);
    }
    __syncthreads();
    short8 af[4], bf[4];
#pragma unroll
    for (int i = 0; i < 4; ++i) {
      af[i] = *(const short8*)(As + (wm * 64 + i * 16 + fr) * 32 + fq * 8);
      bf[i] = *(const short8*)(Bs + (wn * 64 + i * 16 + fr) * 32 + fq * 8);
    }
#pragma unroll
    for (int i = 0; i < 4; ++i)
#pragma unroll
      for (int j = 0; j < 4; ++j)
        acc[i][j] = __builtin_amdgcn_mfma_f32_16x16x32_bf16(af[i], bf[j], acc[i][j], 0, 0, 0);
    __syncthreads();
  }
  if (n0 < 2048) {  // k/v projection tiles
#pragma unroll
    for (int i = 0; i < 4; ++i) {
      const int mbase = m0 + wm * 64 + i * 16 + fq * 4;
#pragma unroll
      for (int j = 0; j < 4; ++j) {
        const int n = n0 + wn * 64 + j * 16 + fr;
        const int h = (n >> 6) & 15, dk = n & 63;
        float* dst = outk + (size_t)(n >> 10) * BHTD;
#pragma unroll
        for (int r = 0; r < 4; ++r) {
          const int mm = mbase + r;
          const int b = mm >> 8, t = mm & 255;
          dst[(((size_t)b * H + h) * T + t) * DK + dk] = acc[i][j][r];
        }
      }
    }
  } else if (wn == 0) {  // beta/gamma tile
    const int h = fr;
    const float bias_b = b_b[h];
    const float bias_g = ts_b[h] + hd[h];
#pragma unroll
    for (int i = 0; i < 4; ++i) {
      const int mbase = m0 + wm * 64 + i * 16 + fq * 4;
#pragma unroll
      for (int r = 0; r < 4; ++r) {
        const int mm = mbase + r;
        const int b = mm >> 8, t = mm & 255;
        const size_t oo = ((size_t)b * H + h) * T + t;
        beta_out[oo] = 1.f / (1.f + __expf(-(acc[i][0][r] + bias_b)));
        gamma_out[oo] = 1.f / (1.f + __expf(-(acc[i][1][r] + bias_g)));
      }
    }
  }
}

// ---------------------------------------------------------------------------
// Chunked solve v4: P1/P2/P4 on MFMA (bf16 operands, f32 accum), M^T state
// in registers (C/D layout), P3 serial substitution in f32 (readlane).
// ---------------------------------------------------------------------------
__device__ __forceinline__ float rdlane(float x, int j) {
  return __int_as_float(__builtin_amdgcn_readlane(__float_as_int(x), j));
}
// swizzled bf16 tile: element (row, col) at byte row*128 + ((col>>3 ^ row&7)*16) + (col&7)*2
__device__ __forceinline__ int bofs(int row, int col) {
  return row * 128 + ((((col >> 3) ^ (row & 7))) << 4) + ((col & 7) << 1);
}
__device__ __forceinline__ short8 ldsfrag(const __hip_bfloat16* base, int row, int g0) {
  return *(const short8*)((const char*)base + row * 128 + (((g0 ^ (row & 7))) << 4));
}

__global__ __launch_bounds__(256, 2) void solve_write(
    const float* __restrict__ kg, const float* __restrict__ vg,
    const float* __restrict__ betag, const float* __restrict__ gammag,
    const float* __restrict__ Wold, float* __restrict__ Wnew) {
  __shared__ __hip_bfloat16 kCb[64 * 64];  // K  [t][d]
  __shared__ __hip_bfloat16 kTb[64 * 64];  // K^T[d][t]
  __shared__ __hip_bfloat16 Mb[64 * 64];   // M^T[v][d] (bf16 operand copy)
  __shared__ __hip_bfloat16 Ub[64 * 64];   // U^T[v][t]
  __shared__ float Ss[64][68];             // S = K K^T (f32)
  __shared__ float Uu[64][68];             // rhs rows [t][v] (f32)
  __shared__ float s_beta[256], s_cl[256];

  const int tid = threadIdx.x;
  const int bh = blockIdx.x;
  const size_t base = (size_t)bh * T * DK;
  const int lane = tid & 63, w = tid >> 6;
  const int fr = lane & 15, fq = lane >> 4;

  s_beta[tid] = betag[(size_t)bh * T + tid];
  s_cl[tid] = __logf(fmaxf(gammag[(size_t)bh * T + tid], 1e-8f));
  __syncthreads();
  if (tid == 0) {  // serial cumsum (overlaps mreg init below)
    float run = 0.f;
    for (int t = 0; t < T; ++t) { run += s_cl[t]; s_cl[t] = run; }
  }
  // M^T state in regs (C/D layout): mreg[j][r] = M^T[v][d],
  // v = 16w + fq*4 + r, d = 16j + fr.  Init: M^T = Wold.
  f32x4 mreg[4];
  {
    const float* Wo = Wold + (size_t)bh * DK * DK;
#pragma unroll
    for (int j = 0; j < 4; ++j)
#pragma unroll
      for (int r = 0; r < 4; ++r)
        mreg[j][r] = Wo[(size_t)(16 * w + fq * 4 + r) * DK + 16 * j + fr];
  }
  __syncthreads();

  for (int c = 0; c < 4; ++c) {
    const int c0 = c * 64;
    const float oc = (c == 0) ? 0.f : s_cl[c0 - 1];
    const float on = s_cl[c0 + 63];

    {  // ---- stage: normalize k row, write kCb + kTb; dump mreg -> Mb ----
      const int r = tid >> 2, p = tid & 3;
      const float4* kp = (const float4*)(kg + base + (size_t)(c0 + r) * DK + p * 16);
      float4 x0 = kp[0], x1 = kp[1], x2 = kp[2], x3 = kp[3];
      float nrm = x0.x * x0.x + x0.y * x0.y + x0.z * x0.z + x0.w * x0.w +
                  x1.x * x1.x + x1.y * x1.y + x1.z * x1.z + x1.w * x1.w +
                  x2.x * x2.x + x2.y * x2.y + x2.z * x2.z + x2.w * x2.w +
                  x3.x * x3.x + x3.y * x3.y + x3.z * x3.z + x3.w * x3.w;
      nrm += __shfl_xor(nrm, 1, 64);
      nrm += __shfl_xor(nrm, 2, 64);
      const float rn = 1.f / fmaxf(sqrtf(nrm), 1e-12f);
      float kvf[16] = {x0.x * rn, x0.y * rn, x0.z * rn, x0.w * rn,
                       x1.x * rn, x1.y * rn, x1.z * rn, x1.w * rn,
                       x2.x * rn, x2.y * rn, x2.z * rn, x2.w * rn,
                       x3.x * rn, x3.y * rn, x3.z * rn, x3.w * rn};
      short kb[16];
#pragma unroll
      for (int u = 0; u < 16; ++u) {
        __hip_bfloat16 h = __float2bfloat16(kvf[u]);
        kb[u] = *(short*)&h;
      }
      *(short8*)((char*)kCb + r * 128 + (((2 * p) ^ (r & 7)) << 4)) = *(short8*)&kb[0];
      *(short8*)((char*)kCb + r * 128 + (((2 * p + 1) ^ (r & 7)) << 4)) = *(short8*)&kb[8];
#pragma unroll
      for (int u = 0; u < 16; ++u)
        *(short*)((char*)kTb + bofs(16 * p + u, r)) = kb[u];
      // Mb[v][d] from mreg
#pragma unroll
      for (int j = 0; j < 4; ++j)
#pragma unroll
        for (int rr = 0; rr < 4; ++rr) {
          __hip_bfloat16 h = __float2bfloat16(mreg[j][rr]);
          *(short*)((char*)Mb + bofs(16 * w + fq * 4 + rr, 16 * j + fr)) = *(short*)&h;
        }
    }
    __syncthreads();

    {  // ---- P1 + P2 via MFMA; wave w owns rows 16w..16w+15 ----
      const short8 af0 = ldsfrag(kCb, 16 * w + fr, fq);
      const short8 af1 = ldsfrag(kCb, 16 * w + fr, 4 + fq);
      const f32x4 zero = {0.f, 0.f, 0.f, 0.f};
      // P1: S rows
#pragma unroll
      for (int j = 0; j < 4; ++j) {
        short8 b0 = ldsfrag(kCb, 16 * j + fr, fq);
        short8 b1 = ldsfrag(kCb, 16 * j + fr, 4 + fq);
        f32x4 s4 = __builtin_amdgcn_mfma_f32_16x16x32_bf16(af0, b0, zero, 0, 0, 0);
        s4 = __builtin_amdgcn_mfma_f32_16x16x32_bf16(af1, b1, s4, 0, 0, 0);
#pragma unroll
        for (int r = 0; r < 4; ++r) Ss[16 * w + fq * 4 + r][16 * j + fr] = s4[r];
      }
      // P2: U = V - eci * K M
      float eci[4];
#pragma unroll
      for (int r = 0; r < 4; ++r) {
        const int gi = c0 + 16 * w + fq * 4 + r;
        eci[r] = __expf((gi == 0) ? 0.f : s_cl[gi - 1] - oc);
      }
#pragma unroll
      for (int j = 0; j < 4; ++j) {
        short8 m0 = ldsfrag(Mb, 16 * j + fr, fq);
        short8 m1 = ldsfrag(Mb, 16 * j + fr, 4 + fq);
        f32x4 u4 = __builtin_amdgcn_mfma_f32_16x16x32_bf16(af0, m0, zero, 0, 0, 0);
        u4 = __builtin_amdgcn_mfma_f32_16x16x32_bf16(af1, m1, u4, 0, 0, 0);
#pragma unroll
        for (int r = 0; r < 4; ++r) {
          const int t = 16 * w + fq * 4 + r;
          const float vv = vg[base + (size_t)(c0 + t) * DK + 16 * j + fr];
          Uu[t][16 * j + fr] = vv - eci[r] * u4[r];
        }
      }
    }
    __syncthreads();

    {  // ---- P3: serial substitution; wave w owns v-slice [16w,16w+16) ----
      const int gi = c0 + lane;
      const int v0 = w * 16;
      float rhs[16];
#pragma unroll
      for (int u = 0; u < 4; ++u)
        *(float4*)&rhs[4 * u] = *(const float4*)&Uu[lane][v0 + 4 * u];
      const float ci = (gi == 0) ? 0.f : s_cl[gi - 1] - oc;
      const float ecl = __expf(ci);
      const float wgt = s_beta[gi] * __expf(-(s_cl[gi] - oc));
      for (int j = 0; j < 63; ++j) {
        const float wj = rdlane(wgt, j);
        const float sv = Ss[j][lane];  // symmetric: = S[lane][j]
        const float co = (lane > j) ? ecl * wj * sv : 0.f;
#pragma unroll
        for (int u = 0; u < 16; ++u) rhs[u] -= co * rdlane(rhs[u], j);
      }
      const float ul = wgt * __expf(on - oc);
#pragma unroll
      for (int u = 0; u < 16; ++u) {
        __hip_bfloat16 h = __float2bfloat16(ul * rhs[u]);
        *(short*)((char*)Ub + bofs(v0 + u, lane)) = *(short*)&h;
      }
    }
    __syncthreads();

    {  // ---- P4: M^T = rc*M^T + U^T K via MFMA (C preloaded) ----
      const float rc = __expf(on - oc);
      const short8 a0 = ldsfrag(Ub, 16 * w + fr, fq);
      const short8 a1 = ldsfrag(Ub, 16 * w + fr, 4 + fq);
#pragma unroll
      for (int j = 0; j < 4; ++j) {
        short8 b0 = ldsfrag(kTb, 16 * j + fr, fq);
        short8 b1 = ldsfrag(kTb, 16 * j + fr, 4 + fq);
        f32x4 c4;
#pragma unroll
        for (int r = 0; r < 4; ++r) c4[r] = rc * mreg[j][r];
        c4 = __builtin_amdgcn_mfma_f32_16x16x32_bf16(a0, b0, c4, 0, 0, 0);
        c4 = __builtin_amdgcn_mfma_f32_16x16x32_bf16(a1, b1, c4, 0, 0, 0);
        mreg[j] = c4;
      }
    }
    __syncthreads();  // protect kCb/kTb/Mb before next stage
  }
  // ---- epilogue: W_new[v][d] = M^T[v][d] = mreg ----
  {
    float* op = Wnew + (size_t)bh * DK * DK;
#pragma unroll
    for (int j = 0; j < 4; ++j)
#pragma unroll
      for (int r = 0; r < 4; ++r)
        op[(size_t)(16 * w + fq * 4 + r) * DK + 16 * j + fr] = mreg[j][r];
  }
}

// ---------------------------------------------------------------------------
extern "C" void kernel_launch(void* const* d_in, const int* in_sizes, int n_in,
                              void* d_out, int out_size, void* d_ws, size_t ws_size,
                              hipStream_t stream) {
  const float* W_old = (const float*)d_in[0];
  const float* content = (const float*)d_in[1];
  const float* k_w = (const float*)d_in[2];
  const float* v_w = (const float*)d_in[3];
  const float* b_w = (const float*)d_in[4];
  const float* b_b = (const float*)d_in[5];
  const float* ts_w = (const float*)d_in[6];
  const float* ts_b = (const float*)d_in[7];
  const float* hd = (const float*)d_in[8];
  float* out = (float*)d_out;

  float* ws_k = (float*)d_ws;
  float* ws_v = ws_k + BHTD;
  float* ws_beta = ws_v + BHTD;
  float* ws_gamma = ws_beta + (size_t)B * H * T;
  __hip_bfloat16* c_bf = (__hip_bfloat16*)(ws_gamma + (size_t)B * H * T);
  __hip_bfloat16* w_bf = c_bf + (size_t)B * T * D;  // 2176 x 2048 region

  cast_all<<<2048, 256, 0, stream>>>(content, k_w, v_w, b_w, ts_w, c_bf, w_bf);
  gemm_bf16<<<dim3(1088), 256, 0, stream>>>(c_bf, w_bf, ws_k, b_b, ts_b, hd,
                                            ws_beta, ws_gamma);
  solve_write<<<dim3(B * H), 256, 0, stream>>>(ws_k, ws_v, ws_beta, ws_gamma,
                                               W_old, out);
}